// Round 13
// baseline (396.459 us; speedup 1.0000x reference)
//
#include <hip/hip_runtime.h>
#include <hip/hip_cooperative_groups.h>

namespace cg = cooperative_groups;

#define B_ 8
#define Q_ 64
#define K_ 512
#define NU_ 512
#define D_ 512

typedef __attribute__((ext_vector_type(8))) _Float16 half8;
typedef __attribute__((ext_vector_type(16))) float floatx16;

#define C2F 2.8853900817779268f  // 2*log2(e)

// ws float region
#define WS_V 0                   // v[0..511], vtot at [512]
#define WS_EQ 640                // Eq: 8*64*512 f32
#define WS_EK (640 + 262144)     // Ek: 8*512*512 f32
#define WS_FLOATS (WS_EK + 2097152)
// ws half region (after floats)
#define ACVT_ELEMS 2359296  // 8 b * 576 rows (512 keys + 64 query) * 512
#define W_ELEMS 262144      // 512*512
#define KT_ELEMS 2097152    // keysT: 8 b * 512 d * 512 k
#define SH_ELEMS 262144     // Sh: 8 b * 64 q * 512 k

#define SMEM_BYTES 18944  // max(scores 18944, proj/ctx 16384, conv 9280)

#define GLD16(gp, lp)                                                         \
  __builtin_amdgcn_global_load_lds(                                           \
      (const __attribute__((address_space(1))) void*)(gp),                    \
      (__attribute__((address_space(3))) void*)(lp), 16, 0, 0)

// 16B-block swizzle (involution): dst block swz(B,row) holds logical block B.
__device__ __forceinline__ int swz(int bb, int row) {
  return (bb & 56) | ((bb ^ row) & 7);
}

// ---------------------------------------------------------------------------
// Phase 1 body: f32->f16 convert (pre-swizzled) + keysT transpose + v.
// Tasks: A [0,1152), Wk [1152,1280), Wq [1280,1408), keysT [1408,1920),
// v = 1920.
// ---------------------------------------------------------------------------
__device__ __forceinline__ void conv_body(
    int task, int t, const float* query, const float* keys,
    const float* Wq, const float* Wk, const float* la, const float* scalar,
    _Float16* Acvt, _Float16* Wkcvt, _Float16* Wqcvt, _Float16* keysT,
    float* v, char* smem) {
  if (task == 1920) {  // v
    float* red = (float*)smem;
    float* red2 = red + 8;
    float x0 = la[t], x1 = la[t + 256];
    float ss = x0 * x0 + x1 * x1;
#pragma unroll
    for (int o = 1; o < 64; o <<= 1) ss += __shfl_xor(ss, o, 64);
    int wave = t >> 6, lane = t & 63;
    if (lane == 0) red[wave] = ss;
    __syncthreads();
    float tot = red[0] + red[1] + red[2] + red[3];
    float sc = rsqrtf(tot) * scalar[0];
    float v0 = x0 * sc, v1 = x1 * sc;
    v[t] = v0;
    v[t + 256] = v1;
    float sv = v0 + v1;
#pragma unroll
    for (int o = 1; o < 64; o <<= 1) sv += __shfl_xor(sv, o, 64);
    if (lane == 0) red2[wave] = sv;
    __syncthreads();
    if (t == 0) v[512] = red2[0] + red2[1] + red2[2] + red2[3];
    return;
  }
  if (task >= 1408) {  // keysT transpose
    _Float16(*sT)[72] = (_Float16(*)[72])smem;
    int j = task - 1408;  // [0,512)
    int b = j & 7;
    int tile = j >> 3;  // [0,64)
    int kt = tile & 7, dtt = tile >> 3;
    int k0 = kt * 64, d0 = dtt * 64;
    const float* kb_ = keys + ((size_t)b * 512 + k0) * 512 + d0;
    int rl = t >> 4;        // 0..15
    int cl = (t & 15) * 4;  // 0..60
#pragma unroll
    for (int p = 0; p < 4; p++) {
      float4 x = *reinterpret_cast<const float4*>(
          kb_ + (size_t)(rl + 16 * p) * 512 + cl);
      sT[cl + 0][rl + 16 * p] = (_Float16)x.x;
      sT[cl + 1][rl + 16 * p] = (_Float16)x.y;
      sT[cl + 2][rl + 16 * p] = (_Float16)x.z;
      sT[cl + 3][rl + 16 * p] = (_Float16)x.w;
    }
    __syncthreads();
    int drl = t >> 2;  // 0..63
    int drow = d0 + drl;
#pragma unroll
    for (int e = 0; e < 2; e++) {
      int kb2 = (t & 3) * 2 + e;  // local 16B block 0..7
      int bb = (k0 >> 3) + kb2;   // global k block
      int sb = swz(bb, drow);
      half8 o = *reinterpret_cast<const half8*>(&sT[drl][kb2 * 8]);
      *reinterpret_cast<half8*>(keysT + ((size_t)b * 512 + drow) * 512 +
                                sb * 8) = o;
    }
    return;
  }
  const float* src;
  _Float16* dst;
  int r, bb = t & 63;
  if (task < 1152) {  // A: XCD-pinned per batch
    int b = task & 7;
    int i = task >> 3;
    r = i * 4 + (t >> 6);  // local row [0,576)
    src = (r < 512) ? keys + ((size_t)b * 512 + r) * 512
                    : query + ((size_t)b * 64 + (r - 512)) * 512;
    dst = Acvt + ((size_t)b * 576 + r) * 512;
  } else if (task < 1280) {
    int j = task - 1152;
    r = j * 4 + (t >> 6);
    src = Wk + (size_t)r * 512;
    dst = Wkcvt + (size_t)r * 512;
  } else {
    int j = task - 1280;
    r = j * 4 + (t >> 6);
    src = Wq + (size_t)r * 512;
    dst = Wqcvt + (size_t)r * 512;
  }
  int scol = swz(bb, r) * 8;
  float4 x0 = *reinterpret_cast<const float4*>(src + scol);
  float4 x1 = *reinterpret_cast<const float4*>(src + scol + 4);
  half8 o = {(_Float16)x0.x, (_Float16)x0.y, (_Float16)x0.z, (_Float16)x0.w,
             (_Float16)x1.x, (_Float16)x1.y, (_Float16)x1.z, (_Float16)x1.w};
  *reinterpret_cast<half8*>(dst + bb * 8) = o;
}

// ---------------------------------------------------------------------------
// Phase 2 body: MFMA projection (single-buffered LDS, gld_lds staging,
// XOR-swizzled reads). Task [0,576): b=task&7, rr=task>>3, mtb=rr%9, nt=rr/9.
// ---------------------------------------------------------------------------
__device__ __forceinline__ void proj_body(
    int task, int t, const _Float16* Acvt, const _Float16* Wkcvt,
    const _Float16* Wqcvt, const float* bias, float* Ek, float* Eq,
    char* smem) {
  _Float16* sA = (_Float16*)smem;  // [64][64]
  _Float16* sW = sA + 4096;        // [64][64]
  int b = task & 7;
  int rr = task >> 3;
  int mtb = rr % 9;
  int nt = rr / 9;
  int n0 = nt * 64;
  bool isQ = (mtb == 8);
  const _Float16* Wcvt = isQ ? Wqcvt : Wkcvt;
  size_t mrowbase = (size_t)b * 576 + (size_t)mtb * 64;
  int wave = t >> 6, lane = t & 63;
  int mw = (wave >> 1) * 32, nw = (wave & 1) * 32;
  int lr = lane & 31, g = lane >> 5;
  int arow = mw + lr, wrow = nw + lr;
  int lrow = lane >> 3, lblk = lane & 7;
  const _Float16* gAbase =
      Acvt + (mrowbase + wave * 16 + lrow) * 512 + lblk * 8;
  const _Float16* gWbase =
      Wcvt + ((size_t)(n0 + wave * 16 + lrow)) * 512 + lblk * 8;

  floatx16 acc;
#pragma unroll
  for (int i = 0; i < 16; i++) acc[i] = 0.f;

  for (int kt = 0; kt < 8; kt++) {
    int koff = kt * 64;
    GLD16(gAbase + koff, sA + (wave * 16) * 64);
    GLD16(gAbase + koff + 8 * 512, sA + (wave * 16 + 8) * 64);
    GLD16(gWbase + koff, sW + (wave * 16) * 64);
    GLD16(gWbase + koff + 8 * 512, sW + (wave * 16 + 8) * 64);
    __syncthreads();  // drains gld_lds, staging visible
#pragma unroll
    for (int i = 0; i < 4; i++) {
      int ablk = (((2 * i + g) ^ arow) & 7) * 8 + ((2 * i + g) & ~7) * 8;
      int wblk = (((2 * i + g) ^ wrow) & 7) * 8 + ((2 * i + g) & ~7) * 8;
      half8 af = *reinterpret_cast<const half8*>(&sA[arow * 64 + ablk]);
      half8 wf = *reinterpret_cast<const half8*>(&sW[wrow * 64 + wblk]);
      acc = __builtin_amdgcn_mfma_f32_32x32x16_f16(af, wf, acc, 0, 0, 0);
    }
    __syncthreads();  // reads done before next stage overwrites
  }
  int col = n0 + nw + lr;
  float bv = isQ ? bias[col] : 0.f;
#pragma unroll
  for (int r = 0; r < 16; r++) {
    int lrow_out = mtb * 64 + mw + (r & 3) + 8 * (r >> 2) + 4 * g;
    float e = __builtin_amdgcn_exp2f((acc[r] + bv) * C2F);
    if (isQ)
      Eq[((size_t)b * 64 + (lrow_out - 512)) * NU_ + col] = e;
    else
      Ek[((size_t)b * 512 + lrow_out) * NU_ + col] = e;
  }
}

// ---------------------------------------------------------------------------
// Phase 3 body: scores; writes Sh f16 pre-swizzled. Task [0,2048).
// S[q,k] = vtot - 2 * sum_u v[u] / (1 + Eq[q,u]*Ek[k,u])
// ---------------------------------------------------------------------------
__device__ __forceinline__ void scores_body(
    int task, int t, const float* Eq, const float* Ek, const float* v,
    _Float16* Sh, char* smem) {
  float* sEq = (float*)smem;            // [8][512]
  float* sV = sEq + 8 * 512;            // [512]
  float* sRed = sV + 512;               // [2][8][8]
  int b = task & 7;
  int rrr = task >> 3;
  int qt = rrr & 7, kt = rrr >> 3;
  int q0 = qt * 8, k0 = kt * 16;
  const float4* eqsrc =
      reinterpret_cast<const float4*>(Eq + ((size_t)b * Q_ + q0) * NU_);
#pragma unroll
  for (int i = 0; i < 4; i++)
    reinterpret_cast<float4*>(sEq)[t + 256 * i] = eqsrc[t + 256 * i];
  if (t < 128)
    reinterpret_cast<float4*>(sV)[t] = reinterpret_cast<const float4*>(v)[t];
  float vtot = v[512];
  __syncthreads();

  int wave = t >> 6, lane = t & 63;
  int uw = wave >> 1, kw = wave & 1;
  int klane = lane >> 3, ulane = lane & 7;
  int k = k0 + kw * 8 + klane;
  const float* ekr = Ek + ((size_t)b * K_ + k) * NU_;
  float acc[8] = {};
#pragma unroll 2
  for (int j = 0; j < 8; j++) {
    int u = uw * 256 + ulane * 4 + 32 * j;
    float4 ek4 = *reinterpret_cast<const float4*>(ekr + u);
    float4 v4 = *reinterpret_cast<const float4*>(&sV[u]);
#pragma unroll
    for (int qq = 0; qq < 8; qq++) {
      float4 eq4 = *reinterpret_cast<const float4*>(&sEq[qq * 512 + u]);
      float p0 = fmaf(eq4.x, ek4.x, 1.f);
      float p1 = fmaf(eq4.y, ek4.y, 1.f);
      float p2 = fmaf(eq4.z, ek4.z, 1.f);
      float p3 = fmaf(eq4.w, ek4.w, 1.f);
      float n01 = fmaf(v4.x, p1, v4.y * p0);
      float n23 = fmaf(v4.z, p3, v4.w * p2);
      float r01 = __builtin_amdgcn_rcpf(p0 * p1);
      float r23 = __builtin_amdgcn_rcpf(p2 * p3);
      acc[qq] = fmaf(n01, r01, acc[qq]);
      acc[qq] = fmaf(n23, r23, acc[qq]);
    }
  }
#pragma unroll
  for (int qq = 0; qq < 8; qq++) {
    acc[qq] += __shfl_xor(acc[qq], 1, 64);
    acc[qq] += __shfl_xor(acc[qq], 2, 64);
    acc[qq] += __shfl_xor(acc[qq], 4, 64);
  }
  if (uw == 1 && ulane == 0) {
#pragma unroll
    for (int qq = 0; qq < 8; qq++) sRed[(kw * 8 + klane) * 8 + qq] = acc[qq];
  }
  __syncthreads();
  if (uw == 0 && ulane == 0) {
#pragma unroll
    for (int qq = 0; qq < 8; qq++) {
      float a = acc[qq] + sRed[(kw * 8 + klane) * 8 + qq];
      float sval = fmaf(-2.f, a, vtot);
      int row = q0 + qq;
      int sb = swz(k >> 3, row);
      Sh[((size_t)b * 64 + row) * 512 + sb * 8 + (k & 7)] = (_Float16)sval;
    }
  }
}

// ---------------------------------------------------------------------------
// Phase 4 body: ctx via MFMA (tasks 0..63) + softmax (tasks 64..127).
// ---------------------------------------------------------------------------
__device__ __forceinline__ void ctxsm_body(
    int task, int t, const _Float16* Sh, const _Float16* keysT,
    float* ctx, float* smx, char* smem) {
  if (task >= 64) {  // softmax
    int idx = task - 64;
    int b = idx & 7, qt = idx >> 3;
    int q = qt * 8 + (t >> 5), lg = t & 31;
    const _Float16* srow = Sh + ((size_t)b * 64 + q) * 512;
    float sv[16];
#pragma unroll
    for (int ii = 0; ii < 16; ii++) {
      int kk = lg + ii * 32;
      int sb = swz(kk >> 3, q);
      sv[ii] = (float)srow[sb * 8 + (kk & 7)];
    }
    float m = sv[0];
#pragma unroll
    for (int ii = 1; ii < 16; ii++) m = fmaxf(m, sv[ii]);
#pragma unroll
    for (int o = 1; o < 32; o <<= 1) m = fmaxf(m, __shfl_xor(m, o, 64));
    const float L2E = 1.4426950408889634f;
    float e[16], sum = 0.f;
#pragma unroll
    for (int ii = 0; ii < 16; ii++) {
      e[ii] = __builtin_amdgcn_exp2f((sv[ii] - m) * L2E);
      sum += e[ii];
    }
#pragma unroll
    for (int o = 1; o < 32; o <<= 1) sum += __shfl_xor(sum, o, 64);
    float inv = 1.f / sum;
    float* dst = smx + ((size_t)b * 64 + q) * 512;
#pragma unroll
    for (int ii = 0; ii < 16; ii++) dst[lg + ii * 32] = e[ii] * inv;
    return;
  }
  // MFMA ctx
  _Float16* sA = (_Float16*)smem;  // [64][64]
  _Float16* sW = sA + 4096;
  int b = task & 7, nt = task >> 3;
  int n0 = nt * 64;
  int wave = t >> 6, lane = t & 63;
  int mw = (wave >> 1) * 32, nw = (wave & 1) * 32;
  int lr = lane & 31, g = lane >> 5;
  int arow = mw + lr, wrow = nw + lr;
  int lrow = lane >> 3, lblk = lane & 7;
  const _Float16* gAbase =
      Sh + ((size_t)b * 64 + wave * 16 + lrow) * 512 + lblk * 8;
  const _Float16* gWbase =
      keysT + ((size_t)b * 512 + n0 + wave * 16 + lrow) * 512 + lblk * 8;

  floatx16 acc;
#pragma unroll
  for (int i = 0; i < 16; i++) acc[i] = 0.f;

  for (int kt = 0; kt < 8; kt++) {
    int koff = kt * 64;
    GLD16(gAbase + koff, sA + (wave * 16) * 64);
    GLD16(gAbase + koff + 8 * 512, sA + (wave * 16 + 8) * 64);
    GLD16(gWbase + koff, sW + (wave * 16) * 64);
    GLD16(gWbase + koff + 8 * 512, sW + (wave * 16 + 8) * 64);
    __syncthreads();
#pragma unroll
    for (int i = 0; i < 4; i++) {
      int ablk = (((2 * i + g) ^ arow) & 7) * 8 + ((2 * i + g) & ~7) * 8;
      int wblk = (((2 * i + g) ^ wrow) & 7) * 8 + ((2 * i + g) & ~7) * 8;
      half8 af = *reinterpret_cast<const half8*>(&sA[arow * 64 + ablk]);
      half8 wf = *reinterpret_cast<const half8*>(&sW[wrow * 64 + wblk]);
      acc = __builtin_amdgcn_mfma_f32_32x32x16_f16(af, wf, acc, 0, 0, 0);
    }
    __syncthreads();
  }
  int col = n0 + nw + lr;
#pragma unroll
  for (int r = 0; r < 16; r++) {
    int row = mw + (r & 3) + 8 * (r >> 2) + 4 * g;
    ctx[((size_t)b * 64 + row) * 512 + col] = acc[r];
  }
}

// ---------------------------------------------------------------------------
// Fused cooperative kernel: 1024 blocks (4/CU guaranteed), 4 phases,
// 3 grid syncs. Phase tasks grid-strided.
// ---------------------------------------------------------------------------
__global__ __launch_bounds__(256, 4) void fused_kernel(
    const float* query, const float* keys, const float* Wq, const float* Wk,
    const float* la, const float* nscalar, const float* nbias,
    _Float16* Acvt, _Float16* Wkcvt, _Float16* Wqcvt, _Float16* keysT,
    float* v, float* Eq, float* Ek, _Float16* Sh, float* ctx, float* smx) {
  cg::grid_group grid = cg::this_grid();
  __shared__ __align__(16) char smem[SMEM_BYTES];
  int t = threadIdx.x;
  int bid = blockIdx.x;

  for (int task = bid; task < 1921; task += 1024) {
    __syncthreads();
    conv_body(task, t, query, keys, Wq, Wk, la, nscalar, Acvt, Wkcvt, Wqcvt,
              keysT, v, smem);
  }
  grid.sync();
  if (bid < 576)
    proj_body(bid, t, Acvt, Wkcvt, Wqcvt, nbias, Ek, Eq, smem);
  grid.sync();
  for (int task = bid; task < 2048; task += 1024) {
    __syncthreads();
    scores_body(task, t, Eq, Ek, v, Sh, smem);
  }
  grid.sync();
  if (bid < 128) ctxsm_body(bid, t, Sh, keysT, ctx, smx, smem);
}

// ---------------------------------------------------------------------------
// Fallback standalone kernels (non-cooperative path), same bodies.
// ---------------------------------------------------------------------------
__global__ __launch_bounds__(256) void convert_kernel(
    const float* query, const float* keys, const float* Wq, const float* Wk,
    const float* la, const float* nscalar, _Float16* Acvt, _Float16* Wkcvt,
    _Float16* Wqcvt, _Float16* keysT, float* v) {
  __shared__ __align__(16) char smem[SMEM_BYTES];
  conv_body(blockIdx.x, threadIdx.x, query, keys, Wq, Wk, la, nscalar, Acvt,
            Wkcvt, Wqcvt, keysT, v, smem);
}

__global__ __launch_bounds__(256) void mfma_proj_kernel(
    const _Float16* Acvt, const _Float16* Wkcvt, const _Float16* Wqcvt,
    const float* bias, float* Ek, float* Eq) {
  __shared__ __align__(16) char smem[SMEM_BYTES];
  proj_body(blockIdx.x, threadIdx.x, Acvt, Wkcvt, Wqcvt, bias, Ek, Eq, smem);
}

__global__ __launch_bounds__(256) void scores_kernel(
    const float* Eq, const float* Ek, const float* v, _Float16* Sh) {
  __shared__ __align__(16) char smem[SMEM_BYTES];
  scores_body(blockIdx.x, threadIdx.x, Eq, Ek, v, Sh, smem);
}

__global__ __launch_bounds__(256) void ctxsm_kernel(
    const _Float16* Sh, const _Float16* keysT, float* ctx, float* smx) {
  __shared__ __align__(16) char smem[SMEM_BYTES];
  ctxsm_body(blockIdx.x, threadIdx.x, Sh, keysT, ctx, smx, smem);
}

// ---------------------------------------------------------------------------
extern "C" void kernel_launch(void* const* d_in, const int* in_sizes, int n_in,
                              void* d_out, int out_size, void* d_ws,
                              size_t ws_size, hipStream_t stream) {
  const float* query = (const float*)d_in[0];
  const float* keys = (const float*)d_in[1];
  const float* Wq = (const float*)d_in[2];
  const float* Wk = (const float*)d_in[3];
  const float* la = (const float*)d_in[4];
  const float* nscalar = (const float*)d_in[5];
  const float* nbias = (const float*)d_in[6];

  float* out = (float*)d_out;
  float* ctx = out;
  float* smx = out + (size_t)B_ * Q_ * D_;

  float* ws = (float*)d_ws;
  float* v = ws + WS_V;
  float* Eq = ws + WS_EQ;
  float* Ek = ws + WS_EK;
  _Float16* Acvt = (_Float16*)(ws + WS_FLOATS);
  _Float16* Wkcvt = Acvt + ACVT_ELEMS;
  _Float16* Wqcvt = Wkcvt + W_ELEMS;
  _Float16* keysT = Wqcvt + W_ELEMS;
  _Float16* Sh = keysT + KT_ELEMS;

  void* kargs[] = {&query, &keys, &Wq,    &Wk, &la, &nscalar, &nbias,
                   &Acvt,  &Wkcvt, &Wqcvt, &keysT, &v, &Eq, &Ek,
                   &Sh,    &ctx,  &smx};
  hipError_t err = hipLaunchCooperativeKernel(
      (const void*)fused_kernel, dim3(1024), dim3(256), kargs, 0, stream);
  if (err != hipSuccess) {
    (void)hipGetLastError();  // clear sticky error, use fallback path
    convert_kernel<<<1921, 256, 0, stream>>>(query, keys, Wq, Wk, la, nscalar,
                                             Acvt, Wkcvt, Wqcvt, keysT, v);
    mfma_proj_kernel<<<576, 256, 0, stream>>>(Acvt, Wkcvt, Wqcvt, nbias, Ek,
                                              Eq);
    scores_kernel<<<2048, 256, 0, stream>>>(Eq, Ek, v, Sh);
    ctxsm_kernel<<<128, 256, 0, stream>>>(Sh, keysT, ctx, smx);
  }
}

// Round 14
// 42.074 us; speedup vs baseline: 9.4229x; 9.4229x over previous
//
#include <hip/hip_runtime.h>

#define B_ 8
#define Q_ 64
#define K_ 512
#define NU_ 512
#define D_ 512

typedef __attribute__((ext_vector_type(8))) _Float16 half8;
typedef __attribute__((ext_vector_type(16))) float floatx16;

#define C2F 2.8853900817779268f  // 2*log2(e)

// ws float region
#define WS_V 0                   // v[0..511], vtot at [512]
#define WS_EQ 640                // Eq: 8*64*512 f32
#define WS_EK (640 + 262144)     // Ek: 8*512*512 f32
#define WS_FLOATS (WS_EK + 2097152)
// ws half region (after floats)
#define ACVT_ELEMS 2359296  // 8 b * 576 rows (512 keys + 64 query) * 512
#define W_ELEMS 262144      // 512*512
#define KT_ELEMS 2097152    // keysT: 8 b * 512 d * 512 k
#define SH_ELEMS 262144     // Sh: 8 b * 64 q * 512 k

#define GLD16(gp, lp)                                                         \
  __builtin_amdgcn_global_load_lds(                                           \
      (const __attribute__((address_space(1))) void*)(gp),                    \
      (__attribute__((address_space(3))) void*)(lp), 16, 0, 0)

// 16B-block swizzle (involution): dst block swz(B,row) holds logical block B.
__device__ __forceinline__ int swz(int bb, int row) {
  return (bb & 56) | ((bb ^ row) & 7);
}

// ---------------------------------------------------------------------------
// Kernel 1: f32 -> f16 convert into PRE-SWIZZLED per-batch layout + keysT
// transpose + v. Blocks: A [0,1152), Wk [1152,1280), Wq [1280,1408),
// keysT-transpose [1408,1920), v = 1920. All A/T blocks XCD-pinned (b=bid&7).
// ---------------------------------------------------------------------------
__global__ __launch_bounds__(256) void convert_kernel(
    const float* __restrict__ query, const float* __restrict__ keys,
    const float* __restrict__ Wq, const float* __restrict__ Wk,
    const float* __restrict__ la, const float* __restrict__ scalar,
    _Float16* __restrict__ Acvt, _Float16* __restrict__ Wkcvt,
    _Float16* __restrict__ Wqcvt, _Float16* __restrict__ keysT,
    float* __restrict__ v) {
  int bid = blockIdx.x;
  int t = threadIdx.x;
  __shared__ float red[4], red2[4];
  __shared__ _Float16 sT[64][72];
  if (bid == 1920) {  // v block
    float x0 = la[t], x1 = la[t + 256];
    float ss = x0 * x0 + x1 * x1;
#pragma unroll
    for (int o = 1; o < 64; o <<= 1) ss += __shfl_xor(ss, o, 64);
    int wave = t >> 6, lane = t & 63;
    if (lane == 0) red[wave] = ss;
    __syncthreads();
    float tot = red[0] + red[1] + red[2] + red[3];
    float sc = rsqrtf(tot) * scalar[0];
    float v0 = x0 * sc, v1 = x1 * sc;
    v[t] = v0;
    v[t + 256] = v1;
    float sv = v0 + v1;
#pragma unroll
    for (int o = 1; o < 64; o <<= 1) sv += __shfl_xor(sv, o, 64);
    if (lane == 0) red2[wave] = sv;
    __syncthreads();
    if (t == 0) v[512] = red2[0] + red2[1] + red2[2] + red2[3];
    return;
  }
  if (bid >= 1408) {  // keysT transpose blocks
    int j = bid - 1408;  // [0,512)
    int b = j & 7;
    int tile = j >> 3;  // [0,64)
    int kt = tile & 7, dtt = tile >> 3;
    int k0 = kt * 64, d0 = dtt * 64;
    const float* kb_ = keys + ((size_t)b * 512 + k0) * 512 + d0;
    int rl = t >> 4;        // 0..15
    int cl = (t & 15) * 4;  // 0..60
#pragma unroll
    for (int p = 0; p < 4; p++) {
      float4 x =
          *reinterpret_cast<const float4*>(kb_ + (size_t)(rl + 16 * p) * 512 + cl);
      sT[cl + 0][rl + 16 * p] = (_Float16)x.x;
      sT[cl + 1][rl + 16 * p] = (_Float16)x.y;
      sT[cl + 2][rl + 16 * p] = (_Float16)x.z;
      sT[cl + 3][rl + 16 * p] = (_Float16)x.w;
    }
    __syncthreads();
    int drl = t >> 2;  // 0..63
    int drow = d0 + drl;
#pragma unroll
    for (int e = 0; e < 2; e++) {
      int kb2 = (t & 3) * 2 + e;  // local 16B block 0..7
      int bb = (k0 >> 3) + kb2;   // global k block
      int sb = swz(bb, drow);
      half8 o = *reinterpret_cast<const half8*>(&sT[drl][kb2 * 8]);
      *reinterpret_cast<half8*>(keysT + ((size_t)b * 512 + drow) * 512 + sb * 8) = o;
    }
    return;
  }
  const float* src;
  _Float16* dst;
  int r, bb = t & 63;
  if (bid < 1152) {  // A: XCD-pinned per batch
    int b = bid & 7;
    int i = bid >> 3;
    r = i * 4 + (t >> 6);  // local row [0,576)
    src = (r < 512) ? keys + ((size_t)b * 512 + r) * 512
                    : query + ((size_t)b * 64 + (r - 512)) * 512;
    dst = Acvt + ((size_t)b * 576 + r) * 512;
  } else if (bid < 1280) {
    int j = bid - 1152;
    r = j * 4 + (t >> 6);
    src = Wk + (size_t)r * 512;
    dst = Wkcvt + (size_t)r * 512;
  } else {
    int j = bid - 1280;
    r = j * 4 + (t >> 6);
    src = Wq + (size_t)r * 512;
    dst = Wqcvt + (size_t)r * 512;
  }
  int scol = swz(bb, r) * 8;
  float4 x0 = *reinterpret_cast<const float4*>(src + scol);
  float4 x1 = *reinterpret_cast<const float4*>(src + scol + 4);
  half8 o = {(_Float16)x0.x, (_Float16)x0.y, (_Float16)x0.z, (_Float16)x0.w,
             (_Float16)x1.x, (_Float16)x1.y, (_Float16)x1.z, (_Float16)x1.w};
  *reinterpret_cast<half8*>(dst + bb * 8) = o;
}

// ---------------------------------------------------------------------------
// Kernel 2: MFMA projection (unchanged from round 12). XCD-pinned.
// ---------------------------------------------------------------------------
__global__ __launch_bounds__(256) void mfma_proj_kernel(
    const _Float16* __restrict__ Acvt, const _Float16* __restrict__ Wkcvt,
    const _Float16* __restrict__ Wqcvt, const float* __restrict__ bias,
    float* __restrict__ Ek, float* __restrict__ Eq) {
  __shared__ _Float16 sA[2][64][64];
  __shared__ _Float16 sW[2][64][64];
  int lid = blockIdx.x;  // [0,576)
  int b = lid & 7;
  int rr = lid >> 3;
  int mtb = rr % 9;
  int nt = rr / 9;
  int n0 = nt * 64;
  bool isQ = (mtb == 8);
  const _Float16* Wcvt = isQ ? Wqcvt : Wkcvt;
  size_t mrowbase = (size_t)b * 576 + (size_t)mtb * 64;
  int t = threadIdx.x;
  int wave = t >> 6, lane = t & 63;
  int mw = (wave >> 1) * 32, nw = (wave & 1) * 32;
  int lr = lane & 31, g = lane >> 5;
  int arow = mw + lr, wrow = nw + lr;
  int lrow = lane >> 3, lblk = lane & 7;
  const _Float16* gAbase = Acvt + (mrowbase + wave * 16 + lrow) * 512 + lblk * 8;
  const _Float16* gWbase =
      Wcvt + ((size_t)(n0 + wave * 16 + lrow)) * 512 + lblk * 8;

  floatx16 acc;
#pragma unroll
  for (int i = 0; i < 16; i++) acc[i] = 0.f;

#define STAGE(kt, sel)                                                        \
  {                                                                           \
    int koff = (kt)*64;                                                       \
    GLD16(gAbase + koff, &sA[sel][wave * 16][0]);                             \
    GLD16(gAbase + koff + 8 * 512, &sA[sel][wave * 16 + 8][0]);               \
    GLD16(gWbase + koff, &sW[sel][wave * 16][0]);                             \
    GLD16(gWbase + koff + 8 * 512, &sW[sel][wave * 16 + 8][0]);               \
  }

  STAGE(0, 0);
  for (int kt = 0; kt < 8; kt++) {
    __syncthreads();
    if (kt < 7) STAGE(kt + 1, (kt + 1) & 1);
    int sel = kt & 1;
#pragma unroll
    for (int i = 0; i < 4; i++) {
      int ablk = (((2 * i + g) ^ arow) & 7) * 8 + ((2 * i + g) & ~7) * 8;
      int wblk = (((2 * i + g) ^ wrow) & 7) * 8 + ((2 * i + g) & ~7) * 8;
      half8 af = *reinterpret_cast<const half8*>(&sA[sel][arow][ablk]);
      half8 wf = *reinterpret_cast<const half8*>(&sW[sel][wrow][wblk]);
      acc = __builtin_amdgcn_mfma_f32_32x32x16_f16(af, wf, acc, 0, 0, 0);
    }
  }
#undef STAGE
  int col = n0 + nw + lr;
  float bv = isQ ? bias[col] : 0.f;
#pragma unroll
  for (int r = 0; r < 16; r++) {
    int lrow_out = mtb * 64 + mw + (r & 3) + 8 * (r >> 2) + 4 * g;
    float e = __builtin_amdgcn_exp2f((acc[r] + bv) * C2F);
    if (isQ)
      Eq[((size_t)b * 64 + (lrow_out - 512)) * NU_ + col] = e;
    else
      Ek[((size_t)b * 512 + lrow_out) * NU_ + col] = e;
  }
}

// ---------------------------------------------------------------------------
// Kernel 3: scores; 4-term rational combine (1 rcp per 4 u-terms) +
// launch_bounds(256,8) for full 8 blocks/CU. Writes Sh f16 pre-swizzled.
// S[q,k] = vtot - 2 * sum_u v[u] / (1 + Eq[q,u]*Ek[k,u])
// Overflow note: den = p0*p1*p2*p3 <= (1+e^21.6)^4 ~ 3e37 < f32 max; in the
// saturated regime rcp(inf)=0 reproduces the correct ->0 term limit.
// ---------------------------------------------------------------------------
__global__ __launch_bounds__(256, 8) void scores_kernel(
    const float* __restrict__ Eq, const float* __restrict__ Ek,
    const float* __restrict__ v, _Float16* __restrict__ Sh) {
  __shared__ __align__(16) float sEq[8][NU_];
  __shared__ __align__(16) float sV[NU_];
  __shared__ float sRed[2][8][8];
  int lid = blockIdx.x;
  int b = lid & 7;
  int rrr = lid >> 3;
  int qt = rrr & 7, kt = rrr >> 3;
  int q0 = qt * 8, k0 = kt * 16;
  int t = threadIdx.x;
  const float4* eqsrc =
      reinterpret_cast<const float4*>(Eq + ((size_t)b * Q_ + q0) * NU_);
#pragma unroll
  for (int i = 0; i < 4; i++)
    reinterpret_cast<float4*>(&sEq[0][0])[t + 256 * i] = eqsrc[t + 256 * i];
  if (t < 128)
    reinterpret_cast<float4*>(sV)[t] = reinterpret_cast<const float4*>(v)[t];
  float vtot = v[512];
  __syncthreads();

  int wave = t >> 6, lane = t & 63;
  int uw = wave >> 1, kw = wave & 1;
  int klane = lane >> 3, ulane = lane & 7;
  int k = k0 + kw * 8 + klane;
  const float* ekr = Ek + ((size_t)b * K_ + k) * NU_;
  float acc[8] = {};
#pragma unroll 2
  for (int j = 0; j < 8; j++) {
    int u = uw * 256 + ulane * 4 + 32 * j;
    float4 ek4 = *reinterpret_cast<const float4*>(ekr + u);
    float4 v4 = *reinterpret_cast<const float4*>(&sV[u]);
#pragma unroll
    for (int qq = 0; qq < 8; qq++) {
      float4 eq4 = *reinterpret_cast<const float4*>(&sEq[qq][u]);
      float p0 = fmaf(eq4.x, ek4.x, 1.f);
      float p1 = fmaf(eq4.y, ek4.y, 1.f);
      float p2 = fmaf(eq4.z, ek4.z, 1.f);
      float p3 = fmaf(eq4.w, ek4.w, 1.f);
      float n01 = fmaf(v4.x, p1, v4.y * p0);
      float n23 = fmaf(v4.z, p3, v4.w * p2);
      float p01 = p0 * p1, p23 = p2 * p3;
      float num = fmaf(n01, p23, n23 * p01);
      float r = __builtin_amdgcn_rcpf(p01 * p23);
      acc[qq] = fmaf(num, r, acc[qq]);
    }
  }
#pragma unroll
  for (int qq = 0; qq < 8; qq++) {
    acc[qq] += __shfl_xor(acc[qq], 1, 64);
    acc[qq] += __shfl_xor(acc[qq], 2, 64);
    acc[qq] += __shfl_xor(acc[qq], 4, 64);
  }
  if (uw == 1 && ulane == 0) {
#pragma unroll
    for (int qq = 0; qq < 8; qq++) sRed[kw][klane][qq] = acc[qq];
  }
  __syncthreads();
  if (uw == 0 && ulane == 0) {
#pragma unroll
    for (int qq = 0; qq < 8; qq++) {
      float a = acc[qq] + sRed[kw][klane][qq];
      float sval = fmaf(-2.f, a, vtot);
      int row = q0 + qq;
      int sb = swz(k >> 3, row);
      Sh[((size_t)b * 64 + row) * 512 + sb * 8 + (k & 7)] = (_Float16)sval;
    }
  }
}

// ---------------------------------------------------------------------------
// Kernel 4: ctx via MFMA (blocks 0..63) + softmax (blocks 64..127).
// (unchanged from round 12)
// ---------------------------------------------------------------------------
__global__ __launch_bounds__(256) void ctxsm_kernel(
    const _Float16* __restrict__ Sh, const _Float16* __restrict__ keysT,
    float* __restrict__ ctx, float* __restrict__ smx) {
  __shared__ _Float16 sA[2][64][64];
  __shared__ _Float16 sW[2][64][64];
  int bid = blockIdx.x;
  int t = threadIdx.x;
  if (bid >= 64) {  // ---- softmax blocks ----
    int idx = bid - 64;
    int b = idx & 7, qt = idx >> 3;
    int q = qt * 8 + (t >> 5), lg = t & 31;
    const _Float16* srow = Sh + ((size_t)b * 64 + q) * 512;
    float sv[16];
#pragma unroll
    for (int ii = 0; ii < 16; ii++) {
      int kk = lg + ii * 32;
      int sb = swz(kk >> 3, q);
      sv[ii] = (float)srow[sb * 8 + (kk & 7)];
    }
    float m = sv[0];
#pragma unroll
    for (int ii = 1; ii < 16; ii++) m = fmaxf(m, sv[ii]);
#pragma unroll
    for (int o = 1; o < 32; o <<= 1) m = fmaxf(m, __shfl_xor(m, o, 64));
    const float L2E = 1.4426950408889634f;
    float e[16], sum = 0.f;
#pragma unroll
    for (int ii = 0; ii < 16; ii++) {
      e[ii] = __builtin_amdgcn_exp2f((sv[ii] - m) * L2E);
      sum += e[ii];
    }
#pragma unroll
    for (int o = 1; o < 32; o <<= 1) sum += __shfl_xor(sum, o, 64);
    float inv = 1.f / sum;
    float* dst = smx + ((size_t)b * 64 + q) * 512;
#pragma unroll
    for (int ii = 0; ii < 16; ii++) dst[lg + ii * 32] = e[ii] * inv;
    return;
  }
  // ---- MFMA ctx blocks ----
  int b = bid & 7, nt = bid >> 3;
  int n0 = nt * 64;
  int wave = t >> 6, lane = t & 63;
  int mw = (wave >> 1) * 32, nw = (wave & 1) * 32;
  int lr = lane & 31, g = lane >> 5;
  int arow = mw + lr, wrow = nw + lr;
  int lrow = lane >> 3, lblk = lane & 7;
  const _Float16* gAbase =
      Sh + ((size_t)b * 64 + wave * 16 + lrow) * 512 + lblk * 8;
  const _Float16* gWbase =
      keysT + ((size_t)b * 512 + n0 + wave * 16 + lrow) * 512 + lblk * 8;

  floatx16 acc;
#pragma unroll
  for (int i = 0; i < 16; i++) acc[i] = 0.f;

#define STAGE(kt, sel)                                                        \
  {                                                                           \
    int koff = (kt)*64;                                                       \
    GLD16(gAbase + koff, &sA[sel][wave * 16][0]);                             \
    GLD16(gAbase + koff + 8 * 512, &sA[sel][wave * 16 + 8][0]);               \
    GLD16(gWbase + koff, &sW[sel][wave * 16][0]);                             \
    GLD16(gWbase + koff + 8 * 512, &sW[sel][wave * 16 + 8][0]);               \
  }

  STAGE(0, 0);
  for (int kt = 0; kt < 8; kt++) {
    __syncthreads();
    if (kt < 7) STAGE(kt + 1, (kt + 1) & 1);
    int sel = kt & 1;
#pragma unroll
    for (int i = 0; i < 4; i++) {
      int ablk = (((2 * i + g) ^ arow) & 7) * 8 + ((2 * i + g) & ~7) * 8;
      int wblk = (((2 * i + g) ^ wrow) & 7) * 8 + ((2 * i + g) & ~7) * 8;
      half8 af = *reinterpret_cast<const half8*>(&sA[sel][arow][ablk]);
      half8 wf = *reinterpret_cast<const half8*>(&sW[sel][wrow][wblk]);
      acc = __builtin_amdgcn_mfma_f32_32x32x16_f16(af, wf, acc, 0, 0, 0);
    }
  }
#undef STAGE
  int col = n0 + nw + lr;
#pragma unroll
  for (int r = 0; r < 16; r++) {
    int row = mw + (r & 3) + 8 * (r >> 2) + 4 * g;
    ctx[((size_t)b * 64 + row) * 512 + col] = acc[r];
  }
}

// ---------------------------------------------------------------------------
extern "C" void kernel_launch(void* const* d_in, const int* in_sizes, int n_in,
                              void* d_out, int out_size, void* d_ws,
                              size_t ws_size, hipStream_t stream) {
  const float* query = (const float*)d_in[0];
  const float* keys = (const float*)d_in[1];
  const float* Wq = (const float*)d_in[2];
  const float* Wk = (const float*)d_in[3];
  const float* la = (const float*)d_in[4];
  const float* nscalar = (const float*)d_in[5];
  const float* nbias = (const float*)d_in[6];

  float* out = (float*)d_out;
  float* ctx = out;
  float* smx = out + (size_t)B_ * Q_ * D_;

  float* ws = (float*)d_ws;
  float* v = ws + WS_V;
  float* Eq = ws + WS_EQ;
  float* Ek = ws + WS_EK;
  _Float16* Acvt = (_Float16*)(ws + WS_FLOATS);
  _Float16* Wkcvt = Acvt + ACVT_ELEMS;
  _Float16* Wqcvt = Wkcvt + W_ELEMS;
  _Float16* keysT = Wqcvt + W_ELEMS;
  _Float16* Sh = keysT + KT_ELEMS;

  convert_kernel<<<1921, 256, 0, stream>>>(query, keys, Wq, Wk, la, nscalar,
                                           Acvt, Wkcvt, Wqcvt, keysT, v);
  mfma_proj_kernel<<<576, 256, 0, stream>>>(Acvt, Wkcvt, Wqcvt, nbias, Ek, Eq);
  scores_kernel<<<2048, 256, 0, stream>>>(Eq, Ek, v, Sh);
  ctxsm_kernel<<<128, 256, 0, stream>>>(Sh, keysT, ctx, smx);
}